// Round 7
// baseline (303.742 us; speedup 1.0000x reference)
//
#include <hip/hip_runtime.h>
#include <hip/hip_bf16.h>
#include <math.h>

typedef __attribute__((ext_vector_type(8))) short short8;
typedef __attribute__((ext_vector_type(4))) float f32x4;

#define NT 8   // n-values pipelined per big block

// ---------------------------------------------------------------------------
// pack: Wh/Wl[o'][q] bf16 hi/lo, o' = h*32 + which*16 + d  (which0=lambda_z1)
//       T2[o][q] = theta2[h][q][d];  ob[q] = sum bias_theta*theta2
//       Lp[which][q][o] packed proj weights (0=lambda_x,1=lambda_y,2=theta1)
// ---------------------------------------------------------------------------
__global__ void pack_kernel(const float* __restrict__ lz1,
                            const float* __restrict__ lz2,
                            const float* __restrict__ th2,
                            const float* __restrict__ bth,
                            const float* __restrict__ lx,
                            const float* __restrict__ ly,
                            const float* __restrict__ t1,
                            __hip_bfloat16* __restrict__ Wh,
                            __hip_bfloat16* __restrict__ Wl,
                            float* __restrict__ T2,
                            float* __restrict__ ob,
                            float* __restrict__ Lp) {
    int tid = blockIdx.x * blockDim.x + threadIdx.x;
    int stride = gridDim.x * blockDim.x;
    for (int i = tid; i < 256 * 128; i += stride) {
        int op = i >> 7, q = i & 127;
        int h = op >> 5, wh = (op >> 4) & 1, d = op & 15;
        float v = (wh ? lz2 : lz1)[(h * 128 + q) * 16 + d];
        __hip_bfloat16 hb = __float2bfloat16(v);
        Wh[i] = hb;
        Wl[i] = __float2bfloat16(v - __bfloat162float(hb));
    }
    for (int i = tid; i < 128 * 128; i += stride) {
        int o = i >> 7, q = i & 127;
        int h = o >> 4, d = o & 15;
        T2[i] = th2[(h * 128 + q) * 16 + d];
    }
    for (int i = tid; i < 3 * 128 * 128; i += stride) {
        int which = i >> 14, q = (i >> 7) & 127, o = i & 127;
        int h = o >> 4, d = o & 15;
        const float* S = (which == 0) ? lx : (which == 1) ? ly : t1;
        Lp[i] = S[(h * 128 + q) * 16 + d];
    }
    if (tid < 128) {
        int q = tid;
        float s = 0.f;
#pragma unroll
        for (int h = 0; h < 8; ++h) {
#pragma unroll
            for (int c = 0; c < 4; ++c) {
                float4 a = *(const float4*)&bth[h * 16 + c * 4];
                float4 b = *(const float4*)&th2[(h * 128 + q) * 16 + c * 4];
                s += a.x * b.x + a.y * b.y + a.z * b.z + a.w * b.w;
            }
        }
        ob[q] = s;
    }
}

// ---------------------------------------------------------------------------
// proj: block = 4 rows (n), 128 thr (o). 4 FMAs per streamed weight load.
// which=0: rx = x@lambda_x + b; 1: ry = y@lambda_y + b; 2: xp = x@theta1
// ---------------------------------------------------------------------------
__global__ __launch_bounds__(128) void proj_kernel(const float* __restrict__ x,
                            const float* __restrict__ y,
                            const float* __restrict__ Lp,
                            const float* __restrict__ blx,
                            const float* __restrict__ bly,
                            float* __restrict__ rx,
                            float* __restrict__ ry,
                            float* __restrict__ xp) {
    __shared__ float rows[4][128];
    const int n0 = blockIdx.x * 4;
    const int which = blockIdx.y;
    const float* in = (which == 1) ? y : x;
    const float* L  = Lp + which * 16384;
    const int o = threadIdx.x;
#pragma unroll
    for (int j = 0; j < 4; ++j)
        rows[j][o] = in[(n0 + j) * 128 + o];
    __syncthreads();
    float acc[4] = {0.f, 0.f, 0.f, 0.f};
#pragma unroll 4
    for (int q = 0; q < 128; ++q) {
        float wv = L[q * 128 + o];
#pragma unroll
        for (int j = 0; j < 4; ++j)
            acc[j] = fmaf(rows[j][q], wv, acc[j]);
    }
    float b = (which == 0) ? blx[o] : (which == 1) ? bly[o] : 0.f;
    float* dst = (which == 0) ? rx : (which == 1) ? ry : xp;
#pragma unroll
    for (int j = 0; j < 4; ++j)
        dst[(n0 + j) * 128 + o] = acc[j] + b;
}

// ---------------------------------------------------------------------------
// big v3: block = (64-m tile, 8 n pipelined). Double-buffered LDS z tiles,
// bf16x3 MFMA (swapped operands), loads for n+1 in flight under compute of n.
// Writes w = exp(att - 10) (unnormalized softmax numerator; masked -> 0).
// ---------------------------------------------------------------------------
__global__ __launch_bounds__(256, 2) void big_kernel(
        const float* __restrict__ z,
        const int* __restrict__ mask,
        const __hip_bfloat16* __restrict__ Wh,
        const __hip_bfloat16* __restrict__ Wl,
        const float* __restrict__ rx,
        const float* __restrict__ ry,
        float* __restrict__ w) {
    __shared__ short zsh[2][64 * 128];   // 2 x 16 KB hi
    __shared__ short zsl[2][64 * 128];   // 2 x 16 KB lo
    const int m0 = blockIdx.x * 64;
    const int n0 = blockIdx.y * NT;
    const int tid = threadIdx.x;
    const int og = tid >> 6;
    const int l  = tid & 63;
    const int lg = l >> 4;
    const int lm = l & 15;

    // staging addressing: thread owns row srow (m0+srow), k-segment kseg*32
    const int srow = tid >> 2, kseg = tid & 3;
    const float* zbase = &z[(size_t)(m0 + srow) * 128 + kseg * 32];

    // ---- hoist W-hi fragments for this wave's o-slice (whole kernel) ----
    short8 bhr[2][4][2];
#pragma unroll
    for (int p = 0; p < 2; ++p)
#pragma unroll
        for (int ks = 0; ks < 4; ++ks)
#pragma unroll
            for (int j = 0; j < 2; ++j)
                bhr[p][ks][j] = *(const short8*)&Wh[(size_t)(og * 64 + (p * 2 + j) * 16 + lm) * 128 + ks * 32 + lg * 8];

    // ---- hoist ry gathers (depend only on m) ----
    float4 ryr[2][4];
#pragma unroll
    for (int p = 0; p < 2; ++p)
#pragma unroll
        for (int i = 0; i < 4; ++i)
            ryr[p][i] = *(const float4*)&ry[(size_t)(m0 + i * 16 + lm) * 128 + (og * 2 + p) * 16 + lg * 4];

    float4 zr[8];
#define LOADZ(nn)                                                         \
    {                                                                     \
        const float* p_ = zbase + (size_t)(nn) * 65536;                   \
        _Pragma("unroll")                                                 \
        for (int c_ = 0; c_ < 8; ++c_) zr[c_] = *(const float4*)&p_[c_ * 4]; \
    }

#define CONVERT_WRITE(b)                                                  \
    {                                                                     \
        _Pragma("unroll")                                                 \
        for (int c8 = 0; c8 < 4; ++c8) {                                  \
            float vv[8] = {zr[2 * c8].x, zr[2 * c8].y, zr[2 * c8].z, zr[2 * c8].w, \
                           zr[2 * c8 + 1].x, zr[2 * c8 + 1].y, zr[2 * c8 + 1].z, zr[2 * c8 + 1].w}; \
            union { short8 s; __hip_bfloat16 h[8]; } uh, ul;              \
            _Pragma("unroll")                                             \
            for (int jj = 0; jj < 8; ++jj) {                              \
                float f_ = vv[jj];                                        \
                __hip_bfloat16 hb_ = __float2bfloat16(f_);                \
                uh.h[jj] = hb_;                                           \
                ul.h[jj] = __float2bfloat16(f_ - __bfloat162float(hb_));  \
            }                                                             \
            int cw_ = (kseg * 4 + c8) ^ (srow & 7);                       \
            *(short8*)&zsh[b][srow * 128 + cw_ * 8] = uh.s;               \
            *(short8*)&zsl[b][srow * 128 + cw_ * 8] = ul.s;               \
        }                                                                 \
    }

    // prologue: stage n0 into buf0, start loads for n0+1
    LOADZ(n0);
    CONVERT_WRITE(0);
    LOADZ(n0 + 1);
    __syncthreads();

    for (int t = 0; t < NT; ++t) {
        const int n = n0 + t;
        const int cur = t & 1;
        const int mk = mask[n * 512 + m0 + l];

        // ---- compute tile n from buf[cur] ----
#pragma unroll
        for (int p = 0; p < 2; ++p) {
            const int h = og * 2 + p;
            f32x4 acc[4][2];
#pragma unroll
            for (int i = 0; i < 4; ++i) {
                acc[i][0] = (f32x4){0.f, 0.f, 0.f, 0.f};
                acc[i][1] = (f32x4){0.f, 0.f, 0.f, 0.f};
            }
#pragma unroll
            for (int ks = 0; ks < 4; ++ks) {
                short8 bl[2];
#pragma unroll
                for (int j = 0; j < 2; ++j)
                    bl[j] = *(const short8*)&Wl[(size_t)(og * 64 + (p * 2 + j) * 16 + lm) * 128 + ks * 32 + lg * 8];
                short8 ah[4], al[4];
#pragma unroll
                for (int i = 0; i < 4; ++i) {
                    int row = i * 16 + lm;
                    int cw = (ks * 4 + lg) ^ (row & 7);
                    ah[i] = *(const short8*)&zsh[cur][row * 128 + cw * 8];
                    al[i] = *(const short8*)&zsl[cur][row * 128 + cw * 8];
                }
#pragma unroll
                for (int i = 0; i < 4; ++i)
#pragma unroll
                    for (int j = 0; j < 2; ++j) {
                        acc[i][j] = __builtin_amdgcn_mfma_f32_16x16x32_bf16(bhr[p][ks][j], ah[i], acc[i][j], 0, 0, 0);
                        acc[i][j] = __builtin_amdgcn_mfma_f32_16x16x32_bf16(bhr[p][ks][j], al[i], acc[i][j], 0, 0, 0);
                        acc[i][j] = __builtin_amdgcn_mfma_f32_16x16x32_bf16(bl[j], ah[i], acc[i][j], 0, 0, 0);
                    }
            }

            // ---- epilogue: d-sum in-reg over r, 2 shfl over lg strata ----
            float4 rxt = *(const float4*)&rx[n * 128 + h * 16 + lg * 4];
            const float rxv[4] = {rxt.x, rxt.y, rxt.z, rxt.w};
            float t4[4];
#pragma unroll
            for (int i = 0; i < 4; ++i) {
                const float ryv[4] = {ryr[p][i].x, ryr[p][i].y, ryr[p][i].z, ryr[p][i].w};
                float s = 0.f;
#pragma unroll
                for (int r = 0; r < 4; ++r)
                    s = fmaf(rxv[r] + acc[i][0][r], ryv[r] + acc[i][1][r], s);
                s += __shfl_xor(s, 16);
                s += __shfl_xor(s, 32);
                t4[i] = s;
            }
            float ta = (lg & 1) ? t4[1] : t4[0];
            float tb = (lg & 1) ? t4[3] : t4[2];
            float s  = (lg & 2) ? tb : ta;
            // w = exp(10*tanh(0.25 s) - 10) = exp(-20/(exp(0.5 s)+1))
            float e1 = __expf(0.5f * s);
            float wv = __expf(-20.f / (e1 + 1.f));
            if (mk == 1) wv = 0.f;
            w[((size_t)(h * 512 + n)) * 512 + m0 + l] = wv;
        }

        // ---- stage n+1 into the other buffer, start loads for n+2 ----
        if (t + 1 < NT) {
            CONVERT_WRITE(cur ^ 1);
            if (t + 2 < NT) LOADZ(n0 + t + 2);
        }
        __syncthreads();
    }
#undef LOADZ
#undef CONVERT_WRITE
}

// ---------------------------------------------------------------------------
// softpv: per (h,m): sum_n w, racc_d = sum_n w*xp; rr = racc/sum.
// Block = (16-m tile, h), 256 thr = 16 m x 16 n-strips of 32.
// ---------------------------------------------------------------------------
__global__ __launch_bounds__(256) void softpv_kernel(const float* __restrict__ w,
                                                     const float* __restrict__ xp,
                                                     float* __restrict__ rr) {
    __shared__ float xps[512][16];        // 32 KB
    __shared__ float red[16][16][16];     // 16 KB
    __shared__ float ssum[16][16];        // 1 KB
    const int m0 = blockIdx.x * 16;
    const int h  = blockIdx.y;
    const int t  = threadIdx.x;
    const int ml = t & 15, g = t >> 4;

    for (int idx = t; idx < 512 * 4; idx += 256) {
        int nn = idx >> 2, c = idx & 3;
        *(float4*)&xps[nn][c * 4] = *(const float4*)&xp[nn * 128 + h * 16 + c * 4];
    }
    __syncthreads();

    const float* col = &w[((size_t)h * 512) * 512 + m0 + ml];
    float s = 0.f;
    float racc[16];
#pragma unroll
    for (int dd = 0; dd < 16; ++dd) racc[dd] = 0.f;
    for (int nn = g * 32; nn < g * 32 + 32; ++nn) {
        float e = col[(size_t)nn * 512];
        s += e;
#pragma unroll
        for (int c = 0; c < 4; ++c) {
            float4 xv = *(const float4*)&xps[nn][c * 4];
            racc[c * 4 + 0] = fmaf(e, xv.x, racc[c * 4 + 0]);
            racc[c * 4 + 1] = fmaf(e, xv.y, racc[c * 4 + 1]);
            racc[c * 4 + 2] = fmaf(e, xv.z, racc[c * 4 + 2]);
            racc[c * 4 + 3] = fmaf(e, xv.w, racc[c * 4 + 3]);
        }
    }
    ssum[g][ml] = s;
#pragma unroll
    for (int dd = 0; dd < 16; ++dd) red[g][ml][dd] = racc[dd];
    __syncthreads();

    {
        const int m = t & 15, dd = t >> 4;
        float stot = 0.f;
#pragma unroll
        for (int gg = 0; gg < 16; ++gg) stot += ssum[gg][m];
        float v = 0.f;
#pragma unroll
        for (int gg = 0; gg < 16; ++gg) v += red[gg][m][dd];
        rr[(size_t)(m0 + m) * 128 + h * 16 + dd] = v / stot;
    }
}

// ---------------------------------------------------------------------------
// outg: block = 4 m rows, 128 thr (q). out[m][q] = ob[q] + sum_o rr[m][o]*T2[o][q]
// ---------------------------------------------------------------------------
__global__ __launch_bounds__(128) void outg_kernel(const float* __restrict__ rr,
                            const float* __restrict__ T2,
                            const float* __restrict__ ob,
                            float* __restrict__ out) {
    __shared__ float rrow[4][128];
    const int m0 = blockIdx.x * 4;
    const int q = threadIdx.x;
#pragma unroll
    for (int j = 0; j < 4; ++j)
        rrow[j][q] = rr[(m0 + j) * 128 + q];
    __syncthreads();
    float acc[4] = {0.f, 0.f, 0.f, 0.f};
#pragma unroll 4
    for (int o = 0; o < 128; ++o) {
        float tv = T2[o * 128 + q];
#pragma unroll
        for (int j = 0; j < 4; ++j)
            acc[j] = fmaf(rrow[j][o], tv, acc[j]);
    }
    float b = ob[q];
#pragma unroll
    for (int j = 0; j < 4; ++j)
        out[(m0 + j) * 128 + q] = acc[j] + b;
}

extern "C" void kernel_launch(void* const* d_in, const int* in_sizes, int n_in,
                              void* d_out, int out_size, void* d_ws, size_t ws_size,
                              hipStream_t stream) {
    (void)in_sizes; (void)n_in; (void)out_size; (void)ws_size;
    const float* x   = (const float*)d_in[0];
    const float* y   = (const float*)d_in[1];
    const float* z   = (const float*)d_in[2];
    const int*  mask = (const int*)d_in[3];
    const float* lx  = (const float*)d_in[4];
    const float* ly  = (const float*)d_in[5];
    const float* lz1 = (const float*)d_in[6];
    const float* lz2 = (const float*)d_in[7];
    const float* blx = (const float*)d_in[8];
    const float* bly = (const float*)d_in[9];
    const float* t1  = (const float*)d_in[10];
    const float* t2  = (const float*)d_in[11];
    const float* bth = (const float*)d_in[12];
    float* out = (float*)d_out;

    float* ws = (float*)d_ws;
    float* rx = ws;                               // 65536
    float* ry = rx + 65536;                       // 65536
    float* xp = ry + 65536;                       // 65536
    __hip_bfloat16* Wh = (__hip_bfloat16*)(xp + 65536);         // 32768 bf16
    __hip_bfloat16* Wl = (__hip_bfloat16*)(xp + 65536 + 16384); // 32768 bf16
    float* T2  = xp + 65536 + 32768;              // 16384
    float* ob  = T2 + 16384;                      // 128
    float* Lp  = ob + 128;                        // 49152
    float* wbuf= Lp + 49152;                      // 8*512*512 = 2097152
    float* rr  = wbuf + 2097152;                  // 65536

    pack_kernel<<<dim3(32), dim3(256), 0, stream>>>(lz1, lz2, t2, bth, lx, ly, t1,
                                                    Wh, Wl, T2, ob, Lp);
    proj_kernel<<<dim3(128, 3), dim3(128), 0, stream>>>(x, y, Lp, blx, bly, rx, ry, xp);
    big_kernel<<<dim3(8, 64), dim3(256), 0, stream>>>(z, mask, Wh, Wl, rx, ry, wbuf);
    softpv_kernel<<<dim3(32, 8), dim3(256), 0, stream>>>(wbuf, xp, rr);
    outg_kernel<<<dim3(128), dim3(128), 0, stream>>>(rr, T2, ob, out);
}

// Round 9
// 297.683 us; speedup vs baseline: 1.0204x; 1.0204x over previous
//
#include <hip/hip_runtime.h>
#include <hip/hip_bf16.h>
#include <math.h>

typedef __attribute__((ext_vector_type(8))) short short8;
typedef __attribute__((ext_vector_type(4))) float f32x4;

#define NT 8   // n-values pipelined per big block

// ---------------------------------------------------------------------------
// prep (fused pack+proj, no intermediate Lp):
//  blocks [0,128):  rx = x@lambda_x + b, xp = x@theta1   (dual accumulate)
//  blocks [128,256): ry = y@lambda_y + b
//  blocks [256,384): Wh/Wl[o'][q] bf16 hi/lo (o' = h*32+which*16+d),
//                    T2[o][q] = theta2[h][q][d], ob[q] = sum bth*theta2
// ---------------------------------------------------------------------------
__global__ __launch_bounds__(128) void prep_kernel(
        const float* __restrict__ x,  const float* __restrict__ y,
        const float* __restrict__ lx, const float* __restrict__ ly,
        const float* __restrict__ t1,
        const float* __restrict__ lz1, const float* __restrict__ lz2,
        const float* __restrict__ th2, const float* __restrict__ bth,
        const float* __restrict__ blx, const float* __restrict__ bly,
        __hip_bfloat16* __restrict__ Wh, __hip_bfloat16* __restrict__ Wl,
        float* __restrict__ T2, float* __restrict__ ob,
        float* __restrict__ rx, float* __restrict__ ry, float* __restrict__ xp) {
    const int bid = blockIdx.x;
    const int t = threadIdx.x;
    if (bid < 256) {
        __shared__ float rows[4][128];
        const int role = bid >> 7;              // 0: x, 1: y
        const int n0 = (bid & 127) * 4;
        const float* in = role ? y : x;
        const int o = t, h = o >> 4, d = o & 15;
#pragma unroll
        for (int j = 0; j < 4; ++j)
            rows[j][o] = in[(n0 + j) * 128 + o];
        __syncthreads();
        if (role == 0) {
            float a[4] = {0.f, 0.f, 0.f, 0.f}, b[4] = {0.f, 0.f, 0.f, 0.f};
#pragma unroll 4
            for (int q = 0; q < 128; ++q) {
                float wa = lx[(h * 128 + q) * 16 + d];
                float wb = t1[(h * 128 + q) * 16 + d];
#pragma unroll
                for (int j = 0; j < 4; ++j) {
                    a[j] = fmaf(rows[j][q], wa, a[j]);
                    b[j] = fmaf(rows[j][q], wb, b[j]);
                }
            }
            float bx = blx[o];
#pragma unroll
            for (int j = 0; j < 4; ++j) {
                rx[(n0 + j) * 128 + o] = a[j] + bx;
                xp[(n0 + j) * 128 + o] = b[j];
            }
        } else {
            float a[4] = {0.f, 0.f, 0.f, 0.f};
#pragma unroll 4
            for (int q = 0; q < 128; ++q) {
                float wa = ly[(h * 128 + q) * 16 + d];
#pragma unroll
                for (int j = 0; j < 4; ++j)
                    a[j] = fmaf(rows[j][q], wa, a[j]);
            }
            float by = bly[o];
#pragma unroll
            for (int j = 0; j < 4; ++j)
                ry[(n0 + j) * 128 + o] = a[j] + by;
        }
    } else {
        const int idx = (bid - 256) * 128 + t;  // 0..16383
#pragma unroll
        for (int i = idx; i < 32768; i += 16384) {
            int op = i >> 7, q = i & 127;
            int h = op >> 5, wh = (op >> 4) & 1, d = op & 15;
            float v = (wh ? lz2 : lz1)[(h * 128 + q) * 16 + d];
            __hip_bfloat16 hb = __float2bfloat16(v);
            Wh[i] = hb;
            Wl[i] = __float2bfloat16(v - __bfloat162float(hb));
        }
        {
            int o = idx >> 7, q = idx & 127;
            int h = o >> 4, d = o & 15;
            T2[idx] = th2[(h * 128 + q) * 16 + d];
        }
        if (idx < 128) {
            int q = idx;
            float s = 0.f;
#pragma unroll
            for (int h = 0; h < 8; ++h)
#pragma unroll
                for (int c = 0; c < 4; ++c) {
                    float4 a = *(const float4*)&bth[h * 16 + c * 4];
                    float4 b = *(const float4*)&th2[(h * 128 + q) * 16 + c * 4];
                    s += a.x * b.x + a.y * b.y + a.z * b.z + a.w * b.w;
                }
            ob[q] = s;
        }
    }
}

// ---------------------------------------------------------------------------
// big v4: block = (64-m tile, 8 n pipelined), 4 waves (og = output quarter).
// Double-buffered LDS z tiles (bf16 hi/lo, XOR-swizzled). W streamed from L2
// each use (NO register hoist - R7's hoists spilled: WRITE_SIZE 8->73 MB).
// p-loop inside ks so z fragments are ds_read once per ks (32/wave/t, was 64).
// Writes w = exp(att-10) (unnormalized softmax numerator; masked -> 0).
// ---------------------------------------------------------------------------
__global__ __launch_bounds__(256) void big_kernel(
        const float* __restrict__ z,
        const int* __restrict__ mask,
        const __hip_bfloat16* __restrict__ Wh,
        const __hip_bfloat16* __restrict__ Wl,
        const float* __restrict__ rx,
        const float* __restrict__ ry,
        float* __restrict__ w) {
    __shared__ short zsh[2][64 * 128];   // 2 x 16 KB hi
    __shared__ short zsl[2][64 * 128];   // 2 x 16 KB lo
    const int m0 = blockIdx.x * 64;
    const int n0 = blockIdx.y * NT;
    const int tid = threadIdx.x;
    const int og = tid >> 6;
    const int l  = tid & 63;
    const int lg = l >> 4;
    const int lm = l & 15;

    const int srow = tid >> 2, kseg = tid & 3;
    const float* zbase = &z[(size_t)(m0 + srow) * 128 + kseg * 32];

    // ry depends only on m: hoist (32 VGPR, loaded once per block)
    float4 ryr[2][4];
#pragma unroll
    for (int p = 0; p < 2; ++p)
#pragma unroll
        for (int i = 0; i < 4; ++i)
            ryr[p][i] = *(const float4*)&ry[(size_t)(m0 + i * 16 + lm) * 128 + (og * 2 + p) * 16 + lg * 4];

    float4 zr[8];
#define LOADZ(nn)                                                         \
    {                                                                     \
        const float* p_ = zbase + (size_t)(nn) * 65536;                   \
        _Pragma("unroll")                                                 \
        for (int c_ = 0; c_ < 8; ++c_) zr[c_] = *(const float4*)&p_[c_ * 4]; \
    }

#define CONVERT_WRITE(b)                                                  \
    {                                                                     \
        _Pragma("unroll")                                                 \
        for (int c8 = 0; c8 < 4; ++c8) {                                  \
            float vv[8] = {zr[2 * c8].x, zr[2 * c8].y, zr[2 * c8].z, zr[2 * c8].w, \
                           zr[2 * c8 + 1].x, zr[2 * c8 + 1].y, zr[2 * c8 + 1].z, zr[2 * c8 + 1].w}; \
            union { short8 s; __hip_bfloat16 h[8]; } uh, ul;              \
            _Pragma("unroll")                                             \
            for (int jj = 0; jj < 8; ++jj) {                              \
                float f_ = vv[jj];                                        \
                __hip_bfloat16 hb_ = __float2bfloat16(f_);                \
                uh.h[jj] = hb_;                                           \
                ul.h[jj] = __float2bfloat16(f_ - __bfloat162float(hb_));  \
            }                                                             \
            int cw_ = (kseg * 4 + c8) ^ (srow & 7);                       \
            *(short8*)&zsh[b][srow * 128 + cw_ * 8] = uh.s;               \
            *(short8*)&zsl[b][srow * 128 + cw_ * 8] = ul.s;               \
        }                                                                 \
    }

    LOADZ(n0);
    CONVERT_WRITE(0);
    LOADZ(n0 + 1);
    __syncthreads();

    for (int t = 0; t < NT; ++t) {
        const int n = n0 + t;
        const int cur = t & 1;
        const int mk = mask[n * 512 + m0 + l];

        f32x4 acc[4][4];    // [edge-tile i][pj = p*2+j]
#pragma unroll
        for (int i = 0; i < 4; ++i)
#pragma unroll
            for (int pj = 0; pj < 4; ++pj) acc[i][pj] = (f32x4){0.f, 0.f, 0.f, 0.f};

#pragma unroll
        for (int ks = 0; ks < 4; ++ks) {
            short8 ah[4], al[4];
#pragma unroll
            for (int i = 0; i < 4; ++i) {
                int row = i * 16 + lm;
                int cw = (ks * 4 + lg) ^ (row & 7);
                ah[i] = *(const short8*)&zsh[cur][row * 128 + cw * 8];
                al[i] = *(const short8*)&zsl[cur][row * 128 + cw * 8];
            }
#pragma unroll
            for (int pj = 0; pj < 4; ++pj) {
                size_t off = (size_t)(og * 64 + pj * 16 + lm) * 128 + ks * 32 + lg * 8;
                short8 bh = *(const short8*)&Wh[off];
                short8 bl = *(const short8*)&Wl[off];
#pragma unroll
                for (int i = 0; i < 4; ++i) {
                    acc[i][pj] = __builtin_amdgcn_mfma_f32_16x16x32_bf16(bh, ah[i], acc[i][pj], 0, 0, 0);
                    acc[i][pj] = __builtin_amdgcn_mfma_f32_16x16x32_bf16(bh, al[i], acc[i][pj], 0, 0, 0);
                    acc[i][pj] = __builtin_amdgcn_mfma_f32_16x16x32_bf16(bl, ah[i], acc[i][pj], 0, 0, 0);
                }
            }
        }

        // epilogue: d-sum in-reg over r, 2 shfl over lg strata, per head
#pragma unroll
        for (int p = 0; p < 2; ++p) {
            const int h = og * 2 + p;
            float4 rxt = *(const float4*)&rx[n * 128 + h * 16 + lg * 4];
            const float rxv[4] = {rxt.x, rxt.y, rxt.z, rxt.w};
            float t4[4];
#pragma unroll
            for (int i = 0; i < 4; ++i) {
                const float ryv[4] = {ryr[p][i].x, ryr[p][i].y, ryr[p][i].z, ryr[p][i].w};
                float s = 0.f;
#pragma unroll
                for (int r = 0; r < 4; ++r)
                    s = fmaf(rxv[r] + acc[i][p * 2][r], ryv[r] + acc[i][p * 2 + 1][r], s);
                s += __shfl_xor(s, 16);
                s += __shfl_xor(s, 32);
                t4[i] = s;
            }
            float ta = (lg & 1) ? t4[1] : t4[0];
            float tb = (lg & 1) ? t4[3] : t4[2];
            float s  = (lg & 2) ? tb : ta;
            // w = exp(10*tanh(0.25 s) - 10) = exp(-20/(exp(0.5 s)+1))
            float e1 = __expf(0.5f * s);
            float wv = __expf(-20.f / (e1 + 1.f));
            if (mk == 1) wv = 0.f;
            w[((size_t)(h * 512 + n)) * 512 + m0 + l] = wv;
        }

        if (t + 1 < NT) {
            CONVERT_WRITE(cur ^ 1);
            if (t + 2 < NT) LOADZ(n0 + t + 2);
        }
        __syncthreads();
    }
#undef LOADZ
#undef CONVERT_WRITE
}

// ---------------------------------------------------------------------------
// finish (fused softpv + outg): block = 8-m tile, 256 thr.
// Phase h: stage xp[.,h-slice] in LDS; 32 n-strips x 8 m accumulate
// sum_n w, sum_n w*xp; reduce -> rrs[8][128] in LDS. After all h:
// out[m][q] = ob[q] + sum_o rrs[m][o]*T2[o][q].
// ---------------------------------------------------------------------------
__global__ __launch_bounds__(256) void finish_kernel(
        const float* __restrict__ w,
        const float* __restrict__ xp,
        const float* __restrict__ T2,
        const float* __restrict__ ob,
        float* __restrict__ out) {
    __shared__ float xps[512][16];      // 32 KB
    __shared__ float red[32][8][16];    // 16 KB
    __shared__ float ssum[32][8];       // 1 KB
    __shared__ float rrs[8][128];       // 4 KB
    const int m0 = blockIdx.x * 8;
    const int t  = threadIdx.x;
    const int ml = t & 7, g = t >> 3;   // 32 strips x 16 n

    for (int h = 0; h < 8; ++h) {
        for (int idx = t; idx < 512 * 4; idx += 256) {
            int nn = idx >> 2, c = idx & 3;
            *(float4*)&xps[nn][c * 4] = *(const float4*)&xp[nn * 128 + h * 16 + c * 4];
        }
        __syncthreads();

        const float* col = &w[((size_t)h * 512) * 512 + m0 + ml];
        float s = 0.f;
        float racc[16];
#pragma unroll
        for (int dd = 0; dd < 16; ++dd) racc[dd] = 0.f;
        for (int nn = g * 16; nn < g * 16 + 16; ++nn) {
            float e = col[(size_t)nn * 512];
            s += e;
#pragma unroll
            for (int c = 0; c < 4; ++c) {
                float4 xv = *(const float4*)&xps[nn][c * 4];
                racc[c * 4 + 0] = fmaf(e, xv.x, racc[c * 4 + 0]);
                racc[c * 4 + 1] = fmaf(e, xv.y, racc[c * 4 + 1]);
                racc[c * 4 + 2] = fmaf(e, xv.z, racc[c * 4 + 2]);
                racc[c * 4 + 3] = fmaf(e, xv.w, racc[c * 4 + 3]);
            }
        }
        ssum[g][ml] = s;
#pragma unroll
        for (int dd = 0; dd < 16; ++dd) red[g][ml][dd] = racc[dd];
        __syncthreads();

        if (t < 128) {
            const int m = t & 7, dd = t >> 3;
            float stot = 0.f;
#pragma unroll
            for (int gg = 0; gg < 32; ++gg) stot += ssum[gg][m];
            float v = 0.f;
#pragma unroll
            for (int gg = 0; gg < 32; ++gg) v += red[gg][m][dd];
            rrs[m][h * 16 + dd] = v / stot;
        }
        __syncthreads();
    }

    // outg: thread = (q = t&127, mg = t>>7 covering 4 m rows)
    {
        const int q = t & 127, mg = t >> 7;
        float acc4[4] = {0.f, 0.f, 0.f, 0.f};
        for (int o4 = 0; o4 < 32; ++o4) {
            float tv[4];
#pragma unroll
            for (int k = 0; k < 4; ++k)
                tv[k] = T2[(o4 * 4 + k) * 128 + q];
#pragma unroll
            for (int j = 0; j < 4; ++j) {
                float4 rv = *(const float4*)&rrs[mg * 4 + j][o4 * 4];
                acc4[j] = fmaf(rv.x, tv[0], acc4[j]);
                acc4[j] = fmaf(rv.y, tv[1], acc4[j]);
                acc4[j] = fmaf(rv.z, tv[2], acc4[j]);
                acc4[j] = fmaf(rv.w, tv[3], acc4[j]);
            }
        }
        float b = ob[q];
#pragma unroll
        for (int j = 0; j < 4; ++j)
            out[(m0 + mg * 4 + j) * 128 + q] = acc4[j] + b;
    }
}

extern "C" void kernel_launch(void* const* d_in, const int* in_sizes, int n_in,
                              void* d_out, int out_size, void* d_ws, size_t ws_size,
                              hipStream_t stream) {
    (void)in_sizes; (void)n_in; (void)out_size; (void)ws_size;
    const float* x   = (const float*)d_in[0];
    const float* y   = (const float*)d_in[1];
    const float* z   = (const float*)d_in[2];
    const int*  mask = (const int*)d_in[3];
    const float* lx  = (const float*)d_in[4];
    const float* ly  = (const float*)d_in[5];
    const float* lz1 = (const float*)d_in[6];
    const float* lz2 = (const float*)d_in[7];
    const float* blx = (const float*)d_in[8];
    const float* bly = (const float*)d_in[9];
    const float* t1  = (const float*)d_in[10];
    const float* t2  = (const float*)d_in[11];
    const float* bth = (const float*)d_in[12];
    float* out = (float*)d_out;

    float* ws = (float*)d_ws;
    float* rx = ws;                               // 65536
    float* ry = rx + 65536;                       // 65536
    float* xp = ry + 65536;                       // 65536
    __hip_bfloat16* Wh = (__hip_bfloat16*)(xp + 65536);         // 32768 bf16
    __hip_bfloat16* Wl = (__hip_bfloat16*)(xp + 65536 + 16384); // 32768 bf16
    float* T2  = xp + 65536 + 32768;              // 16384
    float* ob  = T2 + 16384;                      // 128
    float* wbuf= ob + 128;                        // 8*512*512 = 2097152

    prep_kernel<<<dim3(384), dim3(128), 0, stream>>>(
        x, y, lx, ly, t1, lz1, lz2, t2, bth, blx, bly,
        Wh, Wl, T2, ob, rx, ry, xp);
    big_kernel<<<dim3(8, 64), dim3(256), 0, stream>>>(z, mask, Wh, Wl, rx, ry, wbuf);
    finish_kernel<<<dim3(64), dim3(256), 0, stream>>>(wbuf, xp, T2, ob, out);
}